// Round 10
// baseline (2123.988 us; speedup 1.0000x reference)
//
#include <hip/hip_runtime.h>
#include <hip/hip_cooperative_groups.h>

namespace cg = cooperative_groups;

// PointNet++ forward (B=8, N=4096, D=2, F=5) — single cooperative kernel.
// Blocks 0-7: FPS (stage1 streams winners via device-scope progress counters,
// stage2 after). Blocks 8-255: nbr1+conv1 consumers gated per-query on the
// progress counter (hidden under FPS). Then grid-synced phases on all blocks:
// nbr2+conv2 (in-LDS neighbor lists), u+g fused, head.
// Discrete selections bit-exact vs XLA: __fmul_rn/__fadd_rn distances,
// first-max argmax, top-64 lowest-index tie-break.

#define DPP_UMAX(u, ctrl)                                                      \
  do {                                                                         \
    unsigned _o = (unsigned)__builtin_amdgcn_update_dpp(0, (int)(u), (ctrl),   \
                                                        0xf, 0xf, true);       \
    (u) = ((u) > _o) ? (u) : _o;                                               \
  } while (0)

// One FPS stage (r8-proven inner loop). PUB: wave NW-1 banks each winner in
// registers (lane j holds winner with index%64==j) and every 64 iterations
// bulk-stores the chunk + release fence + progress-counter store.
template<int PPT, int T, bool PUB>
__device__ __forceinline__ void fps_stage(
    float (&xr)[PPT], float (&yr)[PPT], int Msel, int t,
    const float* srcx, const float* srcy,      // LDS mirror of stage points
    float* outx, float* outy,                  // LDS winner list (this stage)
    unsigned long long* sp /*[2*NW]*/,
    float2* pq1g, unsigned* prog) {
  constexpr int NW = T / 64;
  constexpr int HP = PPT / 2;
  float lx = srcx[0], ly = srcy[0];
  if (t == 0) { outx[0] = lx; outy[0] = ly; }
  float px = lx, py = ly;                      // publish capture (wave NW-1)
  float d[PPT];
#pragma unroll
  for (int k = 0; k < PPT; ++k) d[k] = 1e9f;

  for (int i = 1; i < Msel; ++i) {
#pragma unroll
    for (int k = 0; k < PPT; ++k) {
      float dx = xr[k] - lx, dy = yr[k] - ly;
      float dd = __fadd_rn(__fmul_rn(dx, dx), __fmul_rn(dy, dy));
      d[k] = fminf(d[k], dd);
    }
    float bvA = d[0]; int bkA = 0;
    float bvB = d[HP]; int bkB = HP;
#pragma unroll
    for (int k = 1; k < HP; ++k) {
      if (d[k] > bvA)      { bvA = d[k];      bkA = k; }
      if (d[HP + k] > bvB) { bvB = d[HP + k]; bkB = HP + k; }
    }
    float bv = bvA; int bk = bkA;
    if (bvB > bvA) { bv = bvB; bk = bkB; }     // tie keeps A = lower indices
    const int bp = t * PPT + bk;
    const unsigned mybits = __float_as_uint(bv);
    unsigned u = mybits;
    DPP_UMAX(u, 0x111);
    DPP_UMAX(u, 0x112);
    DPP_UMAX(u, 0x114);
    DPP_UMAX(u, 0x118);
    DPP_UMAX(u, 0x142);
    DPP_UMAX(u, 0x143);
    const unsigned wvb = (unsigned)__builtin_amdgcn_readlane((int)u, 63);
    const unsigned long long tmask = __ballot(mybits == wvb);
    const int fl = (int)__builtin_ctzll(tmask);
    const int wbp = __builtin_amdgcn_readlane(bp, fl);
    const int par = i & 1;
    if ((t & 63) == 0)
      sp[par * NW + (t >> 6)] =
          ((unsigned long long)wvb << 32) | (unsigned)(~wbp);
    __syncthreads();
    const unsigned long long* sl = &sp[par * NW];
    unsigned long long best = sl[0];
#pragma unroll
    for (int j = 1; j < NW; ++j) {
      unsigned long long v = sl[j];
      best = (v > best) ? v : best;
    }
    const int wi = (int)(~(unsigned)best);
    lx = srcx[wi]; ly = srcy[wi];
    if (t == 0) { outx[i] = lx; outy[i] = ly; }
    if constexpr (PUB) {
      if ((t >> 6) == NW - 1) {                // wave NW-1, uniform branch
        const int lj = t & 63;
        if (lj == (i & 63)) { px = lx; py = ly; }
        if ((i & 63) == 63) {                  // winners [i-63, i] final
          pq1g[(i - 63) + lj] = make_float2(px, py);
          __builtin_amdgcn_fence(__ATOMIC_RELEASE, "agent");
          if (lj == 0)
            __hip_atomic_store(prog, (unsigned)(i + 1), __ATOMIC_RELAXED,
                               __HIP_MEMORY_SCOPE_AGENT);
        }
      }
    }
  }
}

union SharedU {
  struct {
    float sx[4096], sy[4096];
    float wlx[2048], wly[2048];
    float wl2x[512], wl2y[512];
    unsigned long long sp[16];
  } f;                                          // 53.4 KB (fps)
  struct {
    float sW1t[32 * 8]; float sB1[32];
    float sHH[8 * 64 * 36]; int sNbr[8][64];
  } c1;                                         // 77 KB (nbr1+conv1)
  struct {
    float sW1t[64 * 68]; float sB1[64];
    float sHH[8 * 64 * 68]; int sNbr[8][64];
  } c2;                                         // 155.3 KB (nbr2+conv2)
  struct { float su[16 * 128]; } g;             // 8 KB (u+g)
  struct { float gg[256]; float h4[256]; } h;   // 2 KB (head)
};

__global__ __launch_bounds__(512, 1) void mega_kernel(
    const float* __restrict__ pos,   // [8][4096][2]
    const float* __restrict__ xin,   // [8][4096][5]
    float* __restrict__ posq1,       // [8][2048][2]
    float* __restrict__ posq2,       // [8][512][2]
    float* __restrict__ h1,          // [16384][64]
    float* __restrict__ h2,          // [4096][128]
    float* __restrict__ part,        // [256][256]
    unsigned* __restrict__ prog,     // [8]
    const float* __restrict__ w1a, const float* __restrict__ b1a,
    const float* __restrict__ w1b, const float* __restrict__ b1b,
    const float* __restrict__ w2a, const float* __restrict__ b2a,
    const float* __restrict__ w2b, const float* __restrict__ b2b,
    const float* __restrict__ w3a, const float* __restrict__ b3a,
    const float* __restrict__ w3b, const float* __restrict__ b3b,
    const float* __restrict__ w4a, const float* __restrict__ b4a,
    const float* __restrict__ w4b, const float* __restrict__ b4b,
    float* __restrict__ outp) {
  constexpr int N = 4096, M1 = 2048, M2 = 512, T = 512;
  constexpr int PPT = N / T, PPT2 = M1 / T;
  __shared__ SharedU sh;
  const int bid = blockIdx.x, t = threadIdx.x;
  cg::grid_group grid = cg::this_grid();

  // ---- phase A: zero progress counters before anyone can poll
  if (bid < 8 && t == 0)
    __hip_atomic_store(&prog[bid], 0u, __ATOMIC_RELAXED,
                       __HIP_MEMORY_SCOPE_AGENT);
  grid.sync();

  // ---- phase B: FPS (blocks 0-7) || streaming nbr1+conv1 (blocks 8-255)
  if (bid < 8) {
    const int b = bid;
    float xr[PPT], yr[PPT];
    const float4* p4 =
        (const float4*)(pos + (size_t)b * N * 2 + (size_t)t * PPT * 2);
#pragma unroll
    for (int q = 0; q < PPT / 2; ++q) {
      float4 v = p4[q];
      xr[2 * q + 0] = v.x; yr[2 * q + 0] = v.y;
      xr[2 * q + 1] = v.z; yr[2 * q + 1] = v.w;
    }
#pragma unroll
    for (int k = 0; k < PPT; ++k) {
      int pt = t * PPT + k;
      sh.f.sx[pt] = xr[k]; sh.f.sy[pt] = yr[k];
    }
    __syncthreads();
    fps_stage<PPT, T, true>(xr, yr, M1, t, sh.f.sx, sh.f.sy, sh.f.wlx,
                            sh.f.wly, sh.f.sp,
                            (float2*)posq1 + (size_t)b * M1, &prog[b]);
    __syncthreads();
    float x2[PPT2], y2[PPT2];
#pragma unroll
    for (int k = 0; k < PPT2; ++k) {
      x2[k] = sh.f.wlx[t * PPT2 + k];
      y2[k] = sh.f.wly[t * PPT2 + k];
    }
    fps_stage<PPT2, T, false>(x2, y2, M2, t, sh.f.wlx, sh.f.wly, sh.f.wl2x,
                              sh.f.wl2y, sh.f.sp, nullptr, nullptr);
    __syncthreads();
    for (int j = t; j < M2; j += T)
      ((float2*)posq2)[(size_t)b * M2 + j] =
          make_float2(sh.f.wl2x[j], sh.f.wl2y[j]);
    __builtin_amdgcn_fence(__ATOMIC_RELEASE, "agent");
  } else {
    // streaming nbr1 + conv1 consumer
    for (int j = t; j < 7 * 32; j += T) {
      int cc = j >> 5, hh = j & 31;
      sh.c1.sW1t[hh * 8 + cc] = w1a[j];
    }
    if (t < 32) sh.c1.sB1[t] = b1a[t];
    __syncthreads();
    const int wv = t >> 6, lane = t & 63;
    const unsigned long long below = (1ULL << lane) - 1ULL;
    float* hbase = &sh.c1.sHH[wv * 64 * 36];
    int* snb = sh.c1.sNbr[wv];
    float w2r[32];
#pragma unroll
    for (int hh = 0; hh < 32; ++hh) w2r[hh] = w1b[hh * 64 + lane];
    const float b2o = b1b[lane];
    for (int wid = (bid - 8) * 8 + wv; wid < 16384; wid += 1984) {
      const int b = wid >> 11, j = wid & 2047;
      while (__hip_atomic_load(&prog[b], __ATOMIC_RELAXED,
                               __HIP_MEMORY_SCOPE_AGENT) <= (unsigned)j)
        __builtin_amdgcn_s_sleep(2);
      __builtin_amdgcn_fence(__ATOMIC_ACQUIRE, "agent");
      const unsigned long long pk = __hip_atomic_load(
          (const unsigned long long*)(posq1 + 2 * (size_t)wid),
          __ATOMIC_RELAXED, __HIP_MEMORY_SCOPE_AGENT);
      const float qx = __uint_as_float((unsigned)pk);
      const float qy = __uint_as_float((unsigned)(pk >> 32));
      const float* p = pos + (size_t)b * N * 2;
      snb[lane] = -1;
      unsigned bits[64];
      int cnt = 0;
#pragma unroll
      for (int k = 0; k < 64; ++k) {
        int pt = lane + (k << 6);
        float dx = p[pt * 2 + 0] - qx, dy = p[pt * 2 + 1] - qy;
        float dd = __fadd_rn(__fmul_rn(dx, dx), __fmul_rn(dy, dy));
        bool inr = (dd <= 0.04f);
        bits[k] = inr ? __float_as_uint(dd) : 0xFFFFFFFFu;
        cnt += __popcll(__ballot(inr));
      }
      if (cnt <= 64) {
        int base = 0;
#pragma unroll
        for (int k = 0; k < 64; ++k) {
          bool s = (bits[k] != 0xFFFFFFFFu);
          unsigned long long m = __ballot(s);
          if (s) snb[base + __popcll(m & below)] = lane + (k << 6);
          base += __popcll(m);
        }
      } else {
        unsigned lo = 0, hi = __float_as_uint(0.04f);
        while (lo < hi) {
          unsigned mid = lo + ((hi - lo) >> 1);
          int c = 0;
#pragma unroll
          for (int k = 0; k < 64; ++k) c += __popcll(__ballot(bits[k] <= mid));
          if (c >= 64) hi = mid; else lo = mid + 1;
        }
        int cless = 0;
#pragma unroll
        for (int k = 0; k < 64; ++k) cless += __popcll(__ballot(bits[k] < lo));
        const int need = 64 - cless;
        int base = 0, tiecnt = 0;
#pragma unroll
        for (int k = 0; k < 64; ++k) {
          bool tie = (bits[k] == lo);
          unsigned long long tm = __ballot(tie);
          bool s = (bits[k] < lo) ||
                   (tie && (tiecnt + __popcll(tm & below)) < need);
          tiecnt += __popcll(tm);
          unsigned long long m = __ballot(s);
          if (s) snb[base + __popcll(m & below)] = lane + (k << 6);
          base += __popcll(m);
        }
      }
      const int idx = snb[lane];
      const unsigned long long vm = __ballot(idx >= 0);
      const int ii = (idx < 0) ? 0 : idx;
      float in[7];
      {
        const float* xp = xin + ((size_t)b * N + ii) * 5;
#pragma unroll
        for (int c = 0; c < 5; ++c) in[c] = xp[c];
        const float* pp = p + (size_t)ii * 2;
        in[5] = pp[0] - qx;
        in[6] = pp[1] - qy;
      }
#pragma unroll
      for (int hh = 0; hh < 32; hh += 4) {
        float vv[4];
#pragma unroll
        for (int jj = 0; jj < 4; ++jj) {
          float a = sh.c1.sB1[hh + jj];
#pragma unroll
          for (int c = 0; c < 7; ++c)
            a = fmaf(in[c], sh.c1.sW1t[(hh + jj) * 8 + c], a);
          vv[jj] = fmaxf(a, 0.0f);
        }
        *(float4*)&hbase[lane * 36 + hh] =
            make_float4(vv[0], vv[1], vv[2], vv[3]);
      }
      float m = -1e30f;
      for (int n = 0; n < 64; ++n) {
        const float4* hp = (const float4*)&hbase[n * 36];
        float a = b2o;
#pragma unroll
        for (int jj = 0; jj < 8; ++jj) {
          float4 hv = hp[jj];
          a = fmaf(hv.x, w2r[4 * jj + 0], a);
          a = fmaf(hv.y, w2r[4 * jj + 1], a);
          a = fmaf(hv.z, w2r[4 * jj + 2], a);
          a = fmaf(hv.w, w2r[4 * jj + 3], a);
        }
        a = ((vm >> n) & 1ULL) ? a : -1e9f;
        m = fmaxf(m, a);
      }
      h1[(size_t)wid * 64 + lane] = m;
    }
    __builtin_amdgcn_fence(__ATOMIC_RELEASE, "agent");
  }
  __syncthreads();
  grid.sync();
  __builtin_amdgcn_fence(__ATOMIC_ACQUIRE, "agent");

  // ---- phase C: nbr2 + conv2 fused (all 256 blocks, 8 waves, 2 q/wave)
  {
    for (int j = t; j < 66 * 64; j += T) {
      int cc = j >> 6, hh = j & 63;
      sh.c2.sW1t[hh * 68 + cc] = w2a[j];
    }
    if (t < 64) sh.c2.sB1[t] = b2a[t];
    __syncthreads();
    const int wv = t >> 6, lane = t & 63;
    const unsigned long long below = (1ULL << lane) - 1ULL;
    float* hb = &sh.c2.sHH[wv * 64 * 68];
    int* snb = sh.c2.sNbr[wv];
    for (int q = bid * 8 + wv; q < 4096; q += 2048) {
      const int b = q >> 9;
      const float qx = posq2[2 * (size_t)q], qy = posq2[2 * (size_t)q + 1];
      const float* p = posq1 + (size_t)b * 2048 * 2;
      snb[lane] = -1;
      unsigned bits[32];
      int cnt = 0;
#pragma unroll
      for (int k = 0; k < 32; ++k) {
        int pt = lane + (k << 6);
        float dx = p[pt * 2 + 0] - qx, dy = p[pt * 2 + 1] - qy;
        float dd = __fadd_rn(__fmul_rn(dx, dx), __fmul_rn(dy, dy));
        bool inr = (dd <= 0.16f);
        bits[k] = inr ? __float_as_uint(dd) : 0xFFFFFFFFu;
        cnt += __popcll(__ballot(inr));
      }
      if (cnt <= 64) {
        int base = 0;
#pragma unroll
        for (int k = 0; k < 32; ++k) {
          bool s = (bits[k] != 0xFFFFFFFFu);
          unsigned long long m = __ballot(s);
          if (s) snb[base + __popcll(m & below)] = lane + (k << 6);
          base += __popcll(m);
        }
      } else {
        unsigned lo = 0, hi = __float_as_uint(0.16f);
        while (lo < hi) {
          unsigned mid = lo + ((hi - lo) >> 1);
          int c = 0;
#pragma unroll
          for (int k = 0; k < 32; ++k) c += __popcll(__ballot(bits[k] <= mid));
          if (c >= 64) hi = mid; else lo = mid + 1;
        }
        int cless = 0;
#pragma unroll
        for (int k = 0; k < 32; ++k) cless += __popcll(__ballot(bits[k] < lo));
        const int need = 64 - cless;
        int base = 0, tiecnt = 0;
#pragma unroll
        for (int k = 0; k < 32; ++k) {
          bool tie = (bits[k] == lo);
          unsigned long long tm = __ballot(tie);
          bool s = (bits[k] < lo) ||
                   (tie && (tiecnt + __popcll(tm & below)) < need);
          tiecnt += __popcll(tm);
          unsigned long long m = __ballot(s);
          if (s) snb[base + __popcll(m & below)] = lane + (k << 6);
          base += __popcll(m);
        }
      }
      const int idx = snb[lane];
      const unsigned long long vm = __ballot(idx >= 0);
      const int ii = (idx < 0) ? 0 : idx;
      float in[66];
      {
        const float* xp = h1 + ((size_t)b * 2048 + ii) * 64;
#pragma unroll
        for (int c = 0; c < 64; ++c) in[c] = xp[c];
        in[64] = p[ii * 2 + 0] - qx;
        in[65] = p[ii * 2 + 1] - qy;
      }
#pragma unroll
      for (int hh = 0; hh < 64; hh += 4) {
        float vv[4];
#pragma unroll
        for (int jj = 0; jj < 4; ++jj) {
          float a = sh.c2.sB1[hh + jj];
#pragma unroll
          for (int c = 0; c < 66; ++c)
            a = fmaf(in[c], sh.c2.sW1t[(hh + jj) * 68 + c], a);
          vv[jj] = fmaxf(a, 0.0f);
        }
        *(float4*)&hb[lane * 68 + hh] = make_float4(vv[0], vv[1], vv[2], vv[3]);
      }
#pragma unroll
      for (int half = 0; half < 2; ++half) {
        const int o = half * 64 + lane;
        float w2r[64];
#pragma unroll
        for (int hh = 0; hh < 64; ++hh) w2r[hh] = w2b[hh * 128 + o];
        const float b2o = b2b[o];
        float m = -1e30f;
        for (int n = 0; n < 64; ++n) {
          const float4* hp = (const float4*)&hb[n * 68];
          float a = b2o;
#pragma unroll
          for (int jj = 0; jj < 16; ++jj) {
            float4 hv = hp[jj];
            a = fmaf(hv.x, w2r[4 * jj + 0], a);
            a = fmaf(hv.y, w2r[4 * jj + 1], a);
            a = fmaf(hv.z, w2r[4 * jj + 2], a);
            a = fmaf(hv.w, w2r[4 * jj + 3], a);
          }
          a = ((vm >> n) & 1ULL) ? a : -1e9f;
          m = fmaxf(m, a);
        }
        h2[(size_t)q * 128 + o] = m;
      }
    }
    __builtin_amdgcn_fence(__ATOMIC_RELEASE, "agent");
  }
  __syncthreads();
  grid.sync();
  __builtin_amdgcn_fence(__ATOMIC_ACQUIRE, "agent");

  // ---- phase D: u + g fused. Block = 16-point chunk of the 4096 points.
  {
    const int p0 = bid * 16;
#pragma unroll
    for (int r = 0; r < 4; ++r) {
      const int pl = (t >> 7) + r * 4;
      const int hh = t & 127;
      const int p = p0 + pl;
      const float* hp = h2 + (size_t)p * 128;
      float a = b3a[hh];
      for (int c = 0; c < 128; ++c) a = fmaf(hp[c], w3a[c * 128 + hh], a);
      a = fmaf(posq2[2 * (size_t)p + 0], w3a[128 * 128 + hh], a);
      a = fmaf(posq2[2 * (size_t)p + 1], w3a[129 * 128 + hh], a);
      sh.g.su[pl * 128 + hh] = fmaxf(a, 0.0f);
    }
    __syncthreads();
    if (t < 256) {
      const int o = t;
      float w[128];
#pragma unroll
      for (int hh = 0; hh < 128; ++hh) w[hh] = w3b[hh * 256 + o];
      float m = -1e30f;
      for (int pp = 0; pp < 16; ++pp) {
        float a = b3b[o];
        const float4* sp4 = (const float4*)&sh.g.su[pp * 128];
#pragma unroll
        for (int jj = 0; jj < 32; ++jj) {
          float4 v = sp4[jj];
          a = fmaf(v.x, w[4 * jj + 0], a);
          a = fmaf(v.y, w[4 * jj + 1], a);
          a = fmaf(v.z, w[4 * jj + 2], a);
          a = fmaf(v.w, w[4 * jj + 3], a);
        }
        m = fmaxf(m, a);
      }
      part[(size_t)bid * 256 + o] = m;
    }
    __builtin_amdgcn_fence(__ATOMIC_RELEASE, "agent");
  }
  __syncthreads();
  grid.sync();
  __builtin_amdgcn_fence(__ATOMIC_ACQUIRE, "agent");

  // ---- phase E: head (blocks 0-7)
  if (bid < 8) {
    if (t < 256) {
      float m = part[((size_t)bid * 32) * 256 + t];
      for (int c = 1; c < 32; ++c)
        m = fmaxf(m, part[((size_t)bid * 32 + c) * 256 + t]);
      sh.h.gg[t] = m;
    }
    __syncthreads();
    if (t < 256) {
      float a = b4a[t];
      for (int c = 0; c < 256; ++c) a = fmaf(sh.h.gg[c], w4a[c * 256 + t], a);
      sh.h.h4[t] = fmaxf(a, 0.0f);
    }
    __syncthreads();
    if (t < 256) {
#pragma unroll
      for (int jj = 0; jj < 4; ++jj) {
        int o = t + jj * 256;
        float a2 = b4b[o];
        for (int c = 0; c < 256; ++c) a2 = fmaf(sh.h.h4[c], w4b[c * 1024 + o], a2);
        outp[(size_t)bid * 1024 + o] = a2;
      }
    }
  }
}

// ------------------------------------------------------------------ launch
extern "C" void kernel_launch(void* const* d_in, const int* in_sizes, int n_in,
                              void* d_out, int out_size, void* d_ws, size_t ws_size,
                              hipStream_t stream) {
  (void)in_sizes; (void)n_in; (void)out_size; (void)ws_size;
  const float* x   = (const float*)d_in[0];
  const float* pos = (const float*)d_in[1];
  const float* w1a = (const float*)d_in[2];  const float* b1a = (const float*)d_in[3];
  const float* w1b = (const float*)d_in[4];  const float* b1b = (const float*)d_in[5];
  const float* w2a = (const float*)d_in[6];  const float* b2a = (const float*)d_in[7];
  const float* w2b = (const float*)d_in[8];  const float* b2b = (const float*)d_in[9];
  const float* w3a = (const float*)d_in[10]; const float* b3a = (const float*)d_in[11];
  const float* w3b = (const float*)d_in[12]; const float* b3b = (const float*)d_in[13];
  const float* w4a = (const float*)d_in[14]; const float* b4a = (const float*)d_in[15];
  const float* w4b = (const float*)d_in[16]; const float* b4b = (const float*)d_in[17];
  float* outp = (float*)d_out;

  char* ws = (char*)d_ws;
  size_t off = 0;
  float*    posq1 = (float*)(ws + off); off += (size_t)8 * 2048 * 2 * 4;  // 128 KB
  float*    posq2 = (float*)(ws + off); off += (size_t)8 * 512 * 2 * 4;   //  32 KB
  float*    h1    = (float*)(ws + off); off += (size_t)16384 * 64 * 4;    //   4 MB
  float*    h2    = (float*)(ws + off); off += (size_t)4096 * 128 * 4;    //   2 MB
  float*    part  = (float*)(ws + off); off += (size_t)256 * 256 * 4;     // 256 KB
  unsigned* prog  = (unsigned*)(ws + off); off += 8 * 4;

  void* kargs[] = {
      (void*)&pos, (void*)&x, (void*)&posq1, (void*)&posq2, (void*)&h1,
      (void*)&h2, (void*)&part, (void*)&prog,
      (void*)&w1a, (void*)&b1a, (void*)&w1b, (void*)&b1b,
      (void*)&w2a, (void*)&b2a, (void*)&w2b, (void*)&b2b,
      (void*)&w3a, (void*)&b3a, (void*)&w3b, (void*)&b3b,
      (void*)&w4a, (void*)&b4a, (void*)&w4b, (void*)&b4b,
      (void*)&outp};
  hipLaunchCooperativeKernel((void*)mega_kernel, dim3(256), dim3(512), kargs,
                             0, stream);
}